// Round 2
// baseline (1443.448 us; speedup 1.0000x reference)
//
#include <hip/hip_runtime.h>
#include <hip/hip_bf16.h>
#include <math.h>

// Problem constants
// x:(4,128,96,96) gate_w:(8,128,3,3) gate_bias:(8) expert_w:(8,128,128,3,3)
// expert_b:(8,128) shared_w:(128,128,3,3) shared_b:(128)  -> out:(4,128,96,96)

typedef __attribute__((ext_vector_type(8))) short short8;
typedef __attribute__((ext_vector_type(4))) float f32x4;

static __device__ __forceinline__ unsigned short f2bf(float f) {
    unsigned int u = __float_as_uint(f);
    unsigned int r = (u + 0x7FFFu + ((u >> 16) & 1u)) >> 16;
    return (unsigned short)r;
}

// ---------------------------------------------------------------------------
// Prep: expert_w (8,128,128,3,3) + shared_w (128,128,3,3) -> bf16 in
// MFMA-fragment order (unchanged from round 1).
// 16B-chunk index i:  et(81) | wv(4) | kc(4) | h(2) | lane(64)
// ---------------------------------------------------------------------------
__global__ __launch_bounds__(256) void prep_kernel(
    const float* __restrict__ ew, const float* __restrict__ sw,
    unsigned short* __restrict__ pw)
{
    int i = blockIdx.x * 256 + threadIdx.x;      // 16B chunk index
    if (i >= 9 * 9 * 2048) return;
    int lane = i & 63;
    int h    = (i >> 6) & 1;
    int kc   = (i >> 7) & 3;
    int wv   = (i >> 9) & 3;
    int et   = i >> 11;
    int tap  = et % 9;
    int e    = et / 9;
    int lm = lane & 15, lq = lane >> 4;
    int co = wv * 32 + h * 16 + lm;
    int k0 = kc * 32 + lq * 8;
    unsigned short tmp[8];
    #pragma unroll
    for (int d = 0; d < 8; ++d) {
        int k = k0 + d;
        float v = (e < 8) ? ew[((e * 128 + co) * 128 + k) * 9 + tap]
                          : sw[(co * 128 + k) * 9 + tap];
        tmp[d] = f2bf(v);
    }
    *reinterpret_cast<uint4*>(pw + (size_t)i * 8) =
        *reinterpret_cast<const uint4*>(tmp);
}

// ---------------------------------------------------------------------------
// Fused kernel: gate (fp32, identical math to the old gate_kernel) + dense
// MoE conv via implicit-GEMM MFMA with tap-outer loop:
//   - B-fragments (x-patches) cached in registers per tap, reused by all 9
//     "experts" (8 + shared) -> 9x fewer LDS reads than expert-outer.
//   - A-fragments stream from L2 (fragment-ordered pw), double-buffered.
//   - out = sum_e s_e*conv_e + (sum_e s_e*b_e + b_s), bias folded into store.
// ---------------------------------------------------------------------------
__global__ __launch_bounds__(256, 2) void moe_fused_kernel(
    const float* __restrict__ x, const unsigned short* __restrict__ pw,
    const float* __restrict__ gw, const float* __restrict__ gb,
    const float* __restrict__ eb, const float* __restrict__ sb,
    float* __restrict__ out)
{
    __shared__ unsigned short xs[4 * 34 * 136]; // [row(4)][col(34)][ci 128 pad->136]
    __shared__ float sc[8][64];                 // routing scores per pixel
    __shared__ float bia[9][128];               // expert + shared biases
    __shared__ float red[4][64][8];             // gate partial sums

    const int t  = threadIdx.x;
    const int bx = blockIdx.x;
    const int wt = bx % 3;
    const int h2 = (bx / 3) % 48;
    const int b  = bx / 144;
    const int h0 = h2 * 2, w0 = wt * 32;

    // ---- stage x patch (4 rows x 34 cols x 128 ci), fp32 -> bf16, transposed
    const float* xb = x + b * 128 * 9216;
    for (int i = t; i < 17408; i += 256) {
        int ci  = i / 136;
        int rem = i - ci * 136;
        int row = rem / 34;
        int col = rem - row * 34;
        int hh = h0 - 1 + row;
        int ww = w0 - 1 + col;
        float v = 0.0f;
        if (hh >= 0 && hh < 96 && ww >= 0 && ww < 96)
            v = xb[ci * 9216 + hh * 96 + ww];
        xs[(row * 34 + col) * 136 + ci] = f2bf(v);
    }
    // ---- stage biases (experts + shared as e=8)
    for (int i = t; i < 1152; i += 256) {
        int e = i >> 7, co = i & 127;
        bia[e][co] = (e < 8) ? eb[(e << 7) + co] : sb[co];
    }

    const int wv = t >> 6;
    const int l  = t & 63;

    // ================= gate phase (fp32, same math as old gate) =============
    {
        const int gu = __builtin_amdgcn_readfirstlane(wv);
        const int h = h0 + (l >> 5);
        const int w = w0 + (l & 31);
        int off[9]; float msk[9];
        #pragma unroll
        for (int kh = 0; kh < 3; kh++) {
            #pragma unroll
            for (int kw = 0; kw < 3; kw++) {
                int hh = h + kh - 1, ww = w + kw - 1;
                bool valid = (hh >= 0 && hh < 96 && ww >= 0 && ww < 96);
                int hc = min(max(hh, 0), 95), wc = min(max(ww, 0), 95);
                off[kh * 3 + kw] = hc * 96 + wc;
                msk[kh * 3 + kw] = valid ? 1.0f : 0.0f;
            }
        }
        const float* xg = x + (b * 128 + gu * 32) * 9216;
        float a8[8] = {0.f,0.f,0.f,0.f,0.f,0.f,0.f,0.f};
        #pragma unroll 2
        for (int ci = 0; ci < 32; ++ci) {
            const float* xc = xg + ci * 9216;
            float xv[9];
            #pragma unroll
            for (int tap = 0; tap < 9; ++tap) xv[tap] = xc[off[tap]] * msk[tap];
            const float* gwc = gw + (gu * 32 + ci) * 9;   // uniform -> s_load
            #pragma unroll
            for (int e = 0; e < 8; ++e) {
                const float* gwp = gwc + e * 1152;
                #pragma unroll
                for (int tap = 0; tap < 9; ++tap) a8[e] += xv[tap] * gwp[tap];
            }
        }
        #pragma unroll
        for (int e = 0; e < 8; ++e) red[wv][l][e] = a8[e];
    }
    __syncthreads();

    if (t < 64) {
        float s[8], bs[8];
        #pragma unroll
        for (int e = 0; e < 8; e++) {
            float v = red[0][t][e] + red[1][t][e] + red[2][t][e] + red[3][t][e];
            s[e]  = 1.0f / (1.0f + expf(-v));
            bs[e] = s[e] + gb[e];
        }
        int i1 = 0; float b1 = bs[0]; float w1 = s[0];
        #pragma unroll
        for (int e = 1; e < 8; e++)
            if (bs[e] > b1) { b1 = bs[e]; i1 = e; w1 = s[e]; }
        int i2 = -1; float b2 = -1e30f; float w2 = 0.f;
        #pragma unroll
        for (int e = 0; e < 8; e++)
            if (e != i1 && bs[e] > b2) { b2 = bs[e]; i2 = e; w2 = s[e]; }

        float mx = fmaxf(w1, w2);
        float e1 = expf(w1 - mx), e2 = expf(w2 - mx);
        float inv = 1.0f / (e1 + e2);
        float p1 = e1 * inv, p2 = e2 * inv;   // ROUTE_SCALE = 1

        #pragma unroll
        for (int e = 0; e < 8; e++)
            sc[e][t] = (e == i1) ? p1 : ((e == i2) ? p2 : 0.0f);
    }
    __syncthreads();

    // ================= main MFMA loop: tap-outer, expert-inner ==============
    const int lm = l & 15;   // m (A: co) / n (B: pixel) within frag
    const int lq = l >> 4;   // k-subgroup for A/B; row-group for D
    const int bBase = lm * 136 + lq * 8;
    const uint4* pw4 = reinterpret_cast<const uint4*>(pw) + wv * 512 + l;

    f32x4 acc[2][4], accE[2][4];
    #pragma unroll
    for (int i2 = 0; i2 < 2; i2++)
        #pragma unroll
        for (int j = 0; j < 4; j++)
            acc[i2][j] = (f32x4){0.f, 0.f, 0.f, 0.f};
    const f32x4 zero4 = (f32x4){0.f, 0.f, 0.f, 0.f};

    short8 bf[16];          // B-frag cache for one tap: [kc*4+j]
    uint4 afA[8], afB[8];   // A-frag double buffer: [kc*2+h]

#define IDX(e_, tap_) (((e_) * 9 + (tap_)) * 2048)

#define LOADA(dst, off_) {                                                    \
    const uint4* _p = pw4 + (off_);                                           \
    _Pragma("unroll")                                                         \
    for (int q = 0; q < 8; ++q) dst[q] = _p[(q >> 1) * 128 + (q & 1) * 64];   \
}

#define LOADB(tap_) {                                                         \
    const int kh_ = (tap_) / 3, kw_ = (tap_) - kh_ * 3;                       \
    const int xr0_ = kh_ * 4624 + kw_ * 136 + bBase;                          \
    _Pragma("unroll")                                                         \
    for (int kc = 0; kc < 4; ++kc)                                            \
        _Pragma("unroll")                                                     \
        for (int j = 0; j < 4; ++j)                                           \
            bf[kc * 4 + j] = *reinterpret_cast<const short8*>(                \
                &xs[xr0_ + (j >> 1) * 4624 + (j & 1) * 2176 + kc * 32]);      \
}

#define COMPUTE(src, e_) {                                                    \
    {   const short8 a0 = *reinterpret_cast<const short8*>(&src[0]);          \
        const short8 a1 = *reinterpret_cast<const short8*>(&src[1]);          \
        _Pragma("unroll")                                                     \
        for (int j = 0; j < 4; ++j) {                                         \
            accE[0][j] = __builtin_amdgcn_mfma_f32_16x16x32_bf16(             \
                a0, bf[j], zero4, 0, 0, 0);                                   \
            accE[1][j] = __builtin_amdgcn_mfma_f32_16x16x32_bf16(             \
                a1, bf[j], zero4, 0, 0, 0);                                   \
        } }                                                                   \
    _Pragma("unroll")                                                         \
    for (int kc = 1; kc < 4; ++kc) {                                          \
        const short8 a0 = *reinterpret_cast<const short8*>(&src[kc * 2 + 0]); \
        const short8 a1 = *reinterpret_cast<const short8*>(&src[kc * 2 + 1]); \
        _Pragma("unroll")                                                     \
        for (int j = 0; j < 4; ++j) {                                         \
            accE[0][j] = __builtin_amdgcn_mfma_f32_16x16x32_bf16(             \
                a0, bf[kc * 4 + j], accE[0][j], 0, 0, 0);                     \
            accE[1][j] = __builtin_amdgcn_mfma_f32_16x16x32_bf16(             \
                a1, bf[kc * 4 + j], accE[1][j], 0, 0, 0);                     \
        }                                                                     \
    }                                                                         \
    _Pragma("unroll")                                                         \
    for (int j = 0; j < 4; ++j) {                                             \
        if ((e_) < 8) {                                                       \
            const float s_ = sc[e_][j * 16 + lm];                             \
            _Pragma("unroll")                                                 \
            for (int i2 = 0; i2 < 2; ++i2)                                    \
                _Pragma("unroll")                                             \
                for (int rr = 0; rr < 4; ++rr)                                \
                    acc[i2][j][rr] += s_ * accE[i2][j][rr];                   \
        } else {                                                              \
            _Pragma("unroll")                                                 \
            for (int i2 = 0; i2 < 2; ++i2)                                    \
                _Pragma("unroll")                                             \
                for (int rr = 0; rr < 4; ++rr)                                \
                    acc[i2][j][rr] += accE[i2][j][rr];                        \
        }                                                                     \
    }                                                                         \
}

#define STEP(cur, nxt, e_, noff_) { LOADA(nxt, noff_); COMPUTE(cur, e_); }

    LOADA(afA, IDX(0, 0));
    #pragma unroll 1
    for (int tp = 0; tp < 4; ++tp) {
        const int ta = tp * 2, tb = ta + 1;
        LOADB(ta);
        STEP(afA, afB, 0, IDX(1, ta));
        STEP(afB, afA, 1, IDX(2, ta));
        STEP(afA, afB, 2, IDX(3, ta));
        STEP(afB, afA, 3, IDX(4, ta));
        STEP(afA, afB, 4, IDX(5, ta));
        STEP(afB, afA, 5, IDX(6, ta));
        STEP(afA, afB, 6, IDX(7, ta));
        STEP(afB, afA, 7, IDX(8, ta));
        STEP(afA, afB, 8, IDX(0, tb));
        LOADB(tb);
        STEP(afB, afA, 0, IDX(1, tb));
        STEP(afA, afB, 1, IDX(2, tb));
        STEP(afB, afA, 2, IDX(3, tb));
        STEP(afA, afB, 3, IDX(4, tb));
        STEP(afB, afA, 4, IDX(5, tb));
        STEP(afA, afB, 5, IDX(6, tb));
        STEP(afB, afA, 6, IDX(7, tb));
        STEP(afA, afB, 7, IDX(8, tb));
        STEP(afB, afA, 8, IDX(0, tb + 1));   // tp=3 -> prefetch (0,8)
    }
    LOADB(8);
    STEP(afA, afB, 0, IDX(1, 8));
    STEP(afB, afA, 1, IDX(2, 8));
    STEP(afA, afB, 2, IDX(3, 8));
    STEP(afB, afA, 3, IDX(4, 8));
    STEP(afA, afB, 4, IDX(5, 8));
    STEP(afB, afA, 5, IDX(6, 8));
    STEP(afA, afB, 6, IDX(7, 8));
    STEP(afB, afA, 7, IDX(8, 8));
    COMPUTE(afA, 8);
#undef STEP
#undef COMPUTE
#undef LOADB
#undef LOADA
#undef IDX

    // ---- store: out = acc + (sum_e s_e*b_e + b_shared)
    float* ob = out + b * 128 * 9216;
    #pragma unroll
    for (int j = 0; j < 4; ++j) {
        const int p = j * 16 + lm;
        float se[8];
        #pragma unroll
        for (int e = 0; e < 8; ++e) se[e] = sc[e][p];
        const int hh = h0 + (j >> 1);
        const int ww = w0 + (j & 1) * 16 + lm;
        #pragma unroll
        for (int i2 = 0; i2 < 2; ++i2)
            #pragma unroll
            for (int rr = 0; rr < 4; ++rr) {
                const int co = wv * 32 + i2 * 16 + lq * 4 + rr;
                float bt = bia[8][co];
                #pragma unroll
                for (int e = 0; e < 8; ++e) bt += se[e] * bia[e][co];
                ob[co * 9216 + hh * 96 + ww] = acc[i2][j][rr] + bt;
            }
    }
}

// ---------------------------------------------------------------------------
extern "C" void kernel_launch(void* const* d_in, const int* in_sizes, int n_in,
                              void* d_out, int out_size, void* d_ws, size_t ws_size,
                              hipStream_t stream) {
    const float* x  = (const float*)d_in[0];
    const float* gw = (const float*)d_in[1];
    const float* gb = (const float*)d_in[2];
    const float* ew = (const float*)d_in[3];
    const float* eb = (const float*)d_in[4];
    const float* sw = (const float*)d_in[5];
    const float* sb = (const float*)d_in[6];
    float* out = (float*)d_out;

    unsigned short* pw = (unsigned short*)d_ws;                  // 2,654,208 B

    prep_kernel<<<648, 256, 0, stream>>>(ew, sw, pw);
    moe_fused_kernel<<<576, 256, 0, stream>>>(x, pw, gw, gb, eb, sb, out);
}

// Round 3
// 275.750 us; speedup vs baseline: 5.2346x; 5.2346x over previous
//
#include <hip/hip_runtime.h>
#include <hip/hip_bf16.h>
#include <math.h>

// Problem constants
// x:(4,128,96,96) gate_w:(8,128,3,3) gate_bias:(8) expert_w:(8,128,128,3,3)
// expert_b:(8,128) shared_w:(128,128,3,3) shared_b:(128)  -> out:(4,128,96,96)

typedef __attribute__((ext_vector_type(8))) short short8;
typedef __attribute__((ext_vector_type(4))) short short4s;
typedef __attribute__((ext_vector_type(4))) float f32x4;

static __device__ __forceinline__ unsigned short f2bf(float f) {
    unsigned int u = __float_as_uint(f);
    unsigned int r = (u + 0x7FFFu + ((u >> 16) & 1u)) >> 16;
    return (unsigned short)r;
}

// B-fragment load as two ds_read_b64 (xs rows are 8B-aligned, not 16B).
static __device__ __forceinline__ short8 ldsB(const unsigned short* p) {
    short4s lo = *reinterpret_cast<const short4s*>(p);
    short4s hi = *reinterpret_cast<const short4s*>(p + 4);
    return __builtin_shufflevector(lo, hi, 0, 1, 2, 3, 4, 5, 6, 7);
}

// ---------------------------------------------------------------------------
// Prep: expert_w (8,128,128,3,3) + shared_w (128,128,3,3) -> bf16 in
// MFMA-fragment order (proven in round 1).
// 16B-chunk index i:  et(81) | wv(4) | kc(4) | h(2) | lane(64)
// ---------------------------------------------------------------------------
__global__ __launch_bounds__(256) void prep_kernel(
    const float* __restrict__ ew, const float* __restrict__ sw,
    unsigned short* __restrict__ pw)
{
    int i = blockIdx.x * 256 + threadIdx.x;      // 16B chunk index
    if (i >= 9 * 9 * 2048) return;
    int lane = i & 63;
    int h    = (i >> 6) & 1;
    int kc   = (i >> 7) & 3;
    int wv   = (i >> 9) & 3;
    int et   = i >> 11;
    int tap  = et % 9;
    int e    = et / 9;
    int lm = lane & 15, lq = lane >> 4;
    int co = wv * 32 + h * 16 + lm;
    int k0 = kc * 32 + lq * 8;
    unsigned short tmp[8];
    #pragma unroll
    for (int d = 0; d < 8; ++d) {
        int k = k0 + d;
        float v = (e < 8) ? ew[((e * 128 + co) * 128 + k) * 9 + tap]
                          : sw[(co * 128 + k) * 9 + tap];
        tmp[d] = f2bf(v);
    }
    *reinterpret_cast<uint4*>(pw + (size_t)i * 8) =
        *reinterpret_cast<const uint4*>(tmp);
}

// ---------------------------------------------------------------------------
// Fused kernel: gate (fp32, identical math to the standalone gate) + dense
// MoE conv via implicit-GEMM MFMA (round-1 proven structure):
//   - A-fragments stream from L2 (fragment-ordered pw), double-buffered in
//     registers (16 uint4 = 64 VGPR total, no LDS staging of weights).
//   - x staged once in LDS, pad 132 shorts (264 B) -> B reads are 2x
//     ds_read_b64 with 4-way-max banking (was 8-way at pad 136).
//   - expert-outer loop, accE folded with score+bias at tap==8.
// ---------------------------------------------------------------------------
__global__ __launch_bounds__(256, 3) void moe_fused_kernel(
    const float* __restrict__ x, const unsigned short* __restrict__ pw,
    const float* __restrict__ gw, const float* __restrict__ gb,
    const float* __restrict__ eb, const float* __restrict__ sb,
    float* __restrict__ out)
{
    __shared__ unsigned short xs[136 * 132];    // [pixel(4x34)][ci pad->132]
    __shared__ float sc[8][64];                 // routing scores per pixel
    __shared__ float bia[9][128];               // expert + shared biases
    __shared__ float red[4][64][8];             // gate partial sums

    const int t  = threadIdx.x;
    const int bx = blockIdx.x;
    const int wt = bx % 3;
    const int h2 = (bx / 3) % 48;
    const int b  = bx / 144;
    const int h0 = h2 * 2, w0 = wt * 32;

    // ---- stage x patch (4 rows x 34 cols x 128 ci), fp32 -> bf16, transposed
    const float* xb = x + b * 128 * 9216;
    for (int i = t; i < 17408; i += 256) {
        int ci  = i / 136;
        int pix = i - ci * 136;          // row*34 + col
        int row = pix / 34;
        int col = pix - row * 34;
        int hh = h0 - 1 + row;
        int ww = w0 - 1 + col;
        float v = 0.0f;
        if (hh >= 0 && hh < 96 && ww >= 0 && ww < 96)
            v = xb[ci * 9216 + hh * 96 + ww];
        xs[pix * 132 + ci] = f2bf(v);
    }
    // ---- stage biases (experts + shared as e=8)
    for (int i = t; i < 1152; i += 256) {
        int e = i >> 7, co = i & 127;
        bia[e][co] = (e < 8) ? eb[(e << 7) + co] : sb[co];
    }

    const int wv = t >> 6;
    const int l  = t & 63;

    // ================= gate phase (fp32, same math as standalone) ===========
    {
        const int gu = __builtin_amdgcn_readfirstlane(wv);
        const int h = h0 + (l >> 5);
        const int w = w0 + (l & 31);
        int off[9]; float msk[9];
        #pragma unroll
        for (int kh = 0; kh < 3; kh++) {
            #pragma unroll
            for (int kw = 0; kw < 3; kw++) {
                int hh = h + kh - 1, ww = w + kw - 1;
                bool valid = (hh >= 0 && hh < 96 && ww >= 0 && ww < 96);
                int hc = min(max(hh, 0), 95), wc = min(max(ww, 0), 95);
                off[kh * 3 + kw] = hc * 96 + wc;
                msk[kh * 3 + kw] = valid ? 1.0f : 0.0f;
            }
        }
        const float* xg = x + (b * 128 + gu * 32) * 9216;
        float a8[8] = {0.f,0.f,0.f,0.f,0.f,0.f,0.f,0.f};
        #pragma unroll 2
        for (int ci = 0; ci < 32; ++ci) {
            const float* xc = xg + ci * 9216;
            float xv[9];
            #pragma unroll
            for (int tap = 0; tap < 9; ++tap) xv[tap] = xc[off[tap]] * msk[tap];
            const float* gwc = gw + (gu * 32 + ci) * 9;   // uniform -> s_load
            #pragma unroll
            for (int e = 0; e < 8; ++e) {
                const float* gwp = gwc + e * 1152;
                #pragma unroll
                for (int tap = 0; tap < 9; ++tap) a8[e] += xv[tap] * gwp[tap];
            }
        }
        #pragma unroll
        for (int e = 0; e < 8; ++e) red[wv][l][e] = a8[e];
    }
    __syncthreads();

    if (t < 64) {
        float s[8], bs[8];
        #pragma unroll
        for (int e = 0; e < 8; e++) {
            float v = red[0][t][e] + red[1][t][e] + red[2][t][e] + red[3][t][e];
            s[e]  = 1.0f / (1.0f + expf(-v));
            bs[e] = s[e] + gb[e];
        }
        int i1 = 0; float b1 = bs[0]; float w1 = s[0];
        #pragma unroll
        for (int e = 1; e < 8; e++)
            if (bs[e] > b1) { b1 = bs[e]; i1 = e; w1 = s[e]; }
        int i2 = -1; float b2 = -1e30f; float w2 = 0.f;
        #pragma unroll
        for (int e = 0; e < 8; e++)
            if (e != i1 && bs[e] > b2) { b2 = bs[e]; i2 = e; w2 = s[e]; }

        float mx = fmaxf(w1, w2);
        float e1 = expf(w1 - mx), e2 = expf(w2 - mx);
        float inv = 1.0f / (e1 + e2);
        float p1 = e1 * inv, p2 = e2 * inv;   // ROUTE_SCALE = 1

        #pragma unroll
        for (int e = 0; e < 8; e++)
            sc[e][t] = (e == i1) ? p1 : ((e == i2) ? p2 : 0.0f);
    }
    __syncthreads();

    // ================= main MFMA loop (round-1 structure) ===================
    const int lm = l & 15;   // m (A: co) / n (B: pixel) within frag
    const int lq = l >> 4;   // k-subgroup for A/B; row-group for D
    const int bBase = lm * 132 + lq * 8;
    const uint4* pw4 = reinterpret_cast<const uint4*>(pw) + wv * 512 + l;

    f32x4 acc[2][4], accE[2][4];
    #pragma unroll
    for (int i2 = 0; i2 < 2; i2++)
        #pragma unroll
        for (int j = 0; j < 4; j++) {
            acc[i2][j]  = (f32x4){0.f, 0.f, 0.f, 0.f};
            accE[i2][j] = (f32x4){0.f, 0.f, 0.f, 0.f};
        }

    uint4 afA[8], afB[8];   // A-frag double buffer: [kc*2+h]

#define LOADF(dst, etv) {                                                     \
    const uint4* _p = pw4 + (etv) * 2048;                                     \
    _Pragma("unroll")                                                         \
    for (int q = 0; q < 8; ++q) dst[q] = _p[(q >> 1) * 128 + (q & 1) * 64];   \
}

#define COMPUTE(src, etv) {                                                   \
    const int e_   = (etv) / 9;                                               \
    const int tap_ = (etv) - e_ * 9;                                          \
    const int kh_  = tap_ / 3;                                                \
    const int kw_  = tap_ - kh_ * 3;                                          \
    const int xr0  = kh_ * 4488 + kw_ * 132 + bBase;                          \
    _Pragma("unroll")                                                         \
    for (int kc = 0; kc < 4; ++kc) {                                          \
        const short8 a0 = *reinterpret_cast<const short8*>(&src[kc * 2 + 0]); \
        const short8 a1 = *reinterpret_cast<const short8*>(&src[kc * 2 + 1]); \
        _Pragma("unroll")                                                     \
        for (int j = 0; j < 4; ++j) {                                         \
            const short8 bv = ldsB(                                           \
                &xs[xr0 + (j >> 1) * 4488 + (j & 1) * 2112 + kc * 32]);       \
            accE[0][j] = __builtin_amdgcn_mfma_f32_16x16x32_bf16(             \
                a0, bv, accE[0][j], 0, 0, 0);                                 \
            accE[1][j] = __builtin_amdgcn_mfma_f32_16x16x32_bf16(             \
                a1, bv, accE[1][j], 0, 0, 0);                                 \
        }                                                                     \
    }                                                                         \
    if (tap_ == 8) {  /* end of expert: weighted accumulate */                \
        _Pragma("unroll")                                                     \
        for (int j = 0; j < 4; ++j) {                                         \
            const int p = j * 16 + lm;                                        \
            const float s_ = (e_ < 8) ? sc[e_][p] : 1.0f;                     \
            _Pragma("unroll")                                                 \
            for (int i2 = 0; i2 < 2; ++i2)                                    \
                _Pragma("unroll")                                             \
                for (int rr = 0; rr < 4; ++rr) {                              \
                    const int co_ = wv * 32 + i2 * 16 + lq * 4 + rr;          \
                    acc[i2][j][rr] += s_ * (accE[i2][j][rr] + bia[e_][co_]);  \
                    accE[i2][j][rr] = 0.f;                                    \
                }                                                             \
        }                                                                     \
    }                                                                         \
}

    // barrier-free main loop: 81 (expert,tap) steps, A-frags double-buffered
    LOADF(afA, 0);
    for (int eu = 0; eu < 40; ++eu) {
        const int et0 = eu * 2;
        LOADF(afB, et0 + 1);
        COMPUTE(afA, et0);
        LOADF(afA, et0 + 2);     // et0+2 <= 80
        COMPUTE(afB, et0 + 1);
    }
    COMPUTE(afA, 80);
#undef COMPUTE
#undef LOADF

    // ---- store (D frag: col = lm -> pixel, row = lq*4+rr -> co)
    float* ob = out + b * 128 * 9216;
    #pragma unroll
    for (int i2 = 0; i2 < 2; i2++)
        #pragma unroll
        for (int rr = 0; rr < 4; rr++) {
            const int co = wv * 32 + i2 * 16 + lq * 4 + rr;
            #pragma unroll
            for (int j = 0; j < 4; j++) {
                const int hh = h0 + (j >> 1);
                const int ww = w0 + (j & 1) * 16 + lm;
                ob[co * 9216 + hh * 96 + ww] = acc[i2][j][rr];
            }
        }
}

// ---------------------------------------------------------------------------
extern "C" void kernel_launch(void* const* d_in, const int* in_sizes, int n_in,
                              void* d_out, int out_size, void* d_ws, size_t ws_size,
                              hipStream_t stream) {
    const float* x  = (const float*)d_in[0];
    const float* gw = (const float*)d_in[1];
    const float* gb = (const float*)d_in[2];
    const float* ew = (const float*)d_in[3];
    const float* eb = (const float*)d_in[4];
    const float* sw = (const float*)d_in[5];
    const float* sb = (const float*)d_in[6];
    float* out = (float*)d_out;

    unsigned short* pw = (unsigned short*)d_ws;                  // 2,654,208 B

    prep_kernel<<<648, 256, 0, stream>>>(ew, sw, pw);
    moe_fused_kernel<<<576, 256, 0, stream>>>(x, pw, gw, gb, eb, sb, out);
}

// Round 5
// 221.108 us; speedup vs baseline: 6.5282x; 1.2471x over previous
//
#include <hip/hip_runtime.h>
#include <hip/hip_bf16.h>
#include <math.h>

// Problem constants
// x:(4,128,96,96) gate_w:(8,128,3,3) gate_bias:(8) expert_w:(8,128,128,3,3)
// expert_b:(8,128) shared_w:(128,128,3,3) shared_b:(128)  -> out:(4,128,96,96)

typedef __attribute__((ext_vector_type(8))) short short8;
typedef __attribute__((ext_vector_type(4))) float f32x4;

static __device__ __forceinline__ unsigned short f2bf(float f) {
    unsigned int u = __float_as_uint(f);
    unsigned int r = (u + 0x7FFFu + ((u >> 16) & 1u)) >> 16;
    return (unsigned short)r;
}

// ---------------------------------------------------------------------------
// Merged gate + prep kernel.
//   blocks [0,576):  gate — fp32 conv -> sigmoid -> top2 -> softmax -> scores.
//                    Same math & FP order as the measured R1 gate, but weight
//                    reads are float4 (18 ds_read_b128/ci instead of 72 b32).
//   blocks [576,720): prep — coalesced transpose of expert_w + shared_w into
//                    bf16 pw in MFMA-fragment order (bit-identical layout to
//                    the R1 prep) via an LDS bounce.
// The two halves share an LDS union (45 KB) and have no data dependence.
// ---------------------------------------------------------------------------
__global__ __launch_bounds__(256) void gate_prep_kernel(
    const float* __restrict__ x, const float* __restrict__ gw,
    const float* __restrict__ gb,
    const float* __restrict__ ew, const float* __restrict__ sw,
    float* __restrict__ scores, unsigned short* __restrict__ pw)
{
    __shared__ alignas(16) char smem[45056];
    const int t  = threadIdx.x;
    const int bx = blockIdx.x;

    if (bx >= 576) {
        // =================== prep transpose (144 blocks) ====================
        // pw chunk index: (e*9+tap)*2048 + wv*512 + kc*128 + h*64 + lane
        //   lane = lq*16+lm ; co = wv*32+h*16+lm ; k = kc*32+lq*8+d
        unsigned short* lt2 = reinterpret_cast<unsigned short*>(smem); // [tap][h][lane][d]
        const int pblk = bx - 576;
        const int e  = pblk >> 4;
        const int wv = (pblk >> 2) & 3;
        const int kc = pblk & 3;
        const float* src = (e < 8) ? (ew + e * 147456) : sw;
        const float* sb2 = src + (wv * 32) * 1152 + kc * 288;

        // reads: 32 runs of 288 contiguous floats (coalesced)
        #pragma unroll
        for (int j = 0; j < 36; ++j) {
            int i = t + j * 256;                 // 0..9215
            int co_l = i / 288;
            int r    = i - co_l * 288;           // k_l*9 + tap
            int k_l  = r / 9;
            int tap  = r - k_l * 9;
            float v = sb2[co_l * 1152 + r];
            lt2[tap * 1024 + (co_l >> 4) * 512 +
                ((k_l >> 3) * 16 + (co_l & 15)) * 8 + (k_l & 7)] = f2bf(v);
        }
        __syncthreads();

        // writes: contiguous 1KB uint4 runs per (tap,h) (coalesced)
        uint4* pw16 = reinterpret_cast<uint4*>(pw);
        for (int c = t; c < 1152; c += 256) {
            int tap = c >> 7;
            int rem = c & 127;                   // h*64 + lane
            uint4 val = *reinterpret_cast<const uint4*>(&lt2[tap * 1024 + rem * 8]);
            pw16[(e * 9 + tap) * 2048 + wv * 512 + kc * 128 + rem] = val;
        }
        return;
    }

    // ======================= gate (576 blocks) ==============================
    float* gws = reinterpret_cast<float*>(smem);                    // 9216 f32
    float (*red)[64][8] = reinterpret_cast<float (*)[64][8]>(smem + 36864);

    for (int i = t; i < 9216; i += 256) {
        int ci  = i / 72;
        int r   = i - ci * 72;
        int tap = r >> 3;
        int e   = r & 7;
        gws[i] = gw[(e * 128 + ci) * 9 + tap];
    }
    __syncthreads();

    const int g  = t >> 6;               // ci group (wave id)
    const int p  = t & 63;
    const int wt = bx % 3;
    const int h2 = (bx / 3) % 48;
    const int b  = bx / 144;
    const int h  = h2 * 2 + (p >> 5);
    const int w  = wt * 32 + (p & 31);

    int off[9]; float msk[9];
    #pragma unroll
    for (int kh = 0; kh < 3; kh++) {
        #pragma unroll
        for (int kw = 0; kw < 3; kw++) {
            int hh = h + kh - 1, ww = w + kw - 1;
            bool valid = (hh >= 0 && hh < 96 && ww >= 0 && ww < 96);
            int hc = min(max(hh, 0), 95), wc = min(max(ww, 0), 95);
            off[kh * 3 + kw] = hc * 96 + wc;
            msk[kh * 3 + kw] = valid ? 1.0f : 0.0f;
        }
    }

    const float* xb = x + (b * 128 + g * 32) * 9216;
    float acc[8] = {0.f,0.f,0.f,0.f,0.f,0.f,0.f,0.f};
    #pragma unroll 2
    for (int ci = 0; ci < 32; ci++) {
        const float* xc = xb + ci * 9216;
        const f32x4* wr4 = reinterpret_cast<const f32x4*>(&gws[(g * 32 + ci) * 72]);
        float xv[9];
        #pragma unroll
        for (int tap = 0; tap < 9; tap++) xv[tap] = xc[off[tap]] * msk[tap];
        #pragma unroll
        for (int tap = 0; tap < 9; tap++) {
            const f32x4 wa = wr4[tap * 2];
            const f32x4 wb = wr4[tap * 2 + 1];
            #pragma unroll
            for (int e0 = 0; e0 < 4; e0++) {
                acc[e0]     += xv[tap] * wa[e0];
                acc[e0 + 4] += xv[tap] * wb[e0];
            }
        }
    }

    #pragma unroll
    for (int e = 0; e < 8; e++) red[g][p][e] = acc[e];
    __syncthreads();

    if (t < 64) {
        float s[8], bs[8];
        #pragma unroll
        for (int e = 0; e < 8; e++) {
            float v = red[0][t][e] + red[1][t][e] + red[2][t][e] + red[3][t][e];
            s[e]  = 1.0f / (1.0f + expf(-v));
            bs[e] = s[e] + gb[e];
        }
        // top-1 (ties -> lowest index, matches lax.top_k)
        int i1 = 0; float b1 = bs[0]; float w1 = s[0];
        #pragma unroll
        for (int e = 1; e < 8; e++)
            if (bs[e] > b1) { b1 = bs[e]; i1 = e; w1 = s[e]; }
        int i2 = -1; float b2 = -1e30f; float w2 = 0.f;
        #pragma unroll
        for (int e = 0; e < 8; e++)
            if (e != i1 && bs[e] > b2) { b2 = bs[e]; i2 = e; w2 = s[e]; }

        float mx = fmaxf(w1, w2);
        float e1 = expf(w1 - mx), e2 = expf(w2 - mx);
        float inv = 1.0f / (e1 + e2);
        float p1 = e1 * inv, p2 = e2 * inv;   // ROUTE_SCALE = 1

        const int hh = h2 * 2 + (t >> 5);
        const int ww = wt * 32 + (t & 31);
        int base = b * 8 * 9216 + hh * 96 + ww;
        #pragma unroll
        for (int e = 0; e < 8; e++) {
            float v = (e == i1) ? p1 : ((e == i2) ? p2 : 0.0f);
            scores[base + e * 9216] = v;
        }
    }
}

// ---------------------------------------------------------------------------
// Main: fused dense MoE conv via implicit-GEMM MFMA — byte-identical to the
// measured round-1 kernel (123 us, MfmaUtil 34%).
// ---------------------------------------------------------------------------
__global__ __launch_bounds__(256, 3) void moe_main_kernel(
    const float* __restrict__ x, const unsigned short* __restrict__ pw,
    const float* __restrict__ scores, const float* __restrict__ eb,
    const float* __restrict__ sb, float* __restrict__ out)
{
    __shared__ unsigned short xs[4 * 34 * 136]; // [row(4)][col(34)][ci 128 pad->136]
    __shared__ float sc[8][64];
    __shared__ float bia[9][128];

    const int t  = threadIdx.x;
    const int bx = blockIdx.x;
    const int wt = bx % 3;
    const int h2 = (bx / 3) % 48;
    const int b  = bx / 144;
    const int h0 = h2 * 2, w0 = wt * 32;

    // ---- stage x patch (4 rows x 34 cols x 128 ci), fp32 -> bf16, transposed
    const float* xb = x + b * 128 * 9216;
    for (int i = t; i < 17408; i += 256) {
        int ci  = i / 136;
        int rem = i - ci * 136;
        int row = rem / 34;
        int col = rem - row * 34;
        int hh = h0 - 1 + row;
        int ww = w0 - 1 + col;
        float v = 0.0f;
        if (hh >= 0 && hh < 96 && ww >= 0 && ww < 96)
            v = xb[ci * 9216 + hh * 96 + ww];
        xs[(row * 34 + col) * 136 + ci] = f2bf(v);
    }
    // ---- stage routing scores for the 64 pixels
    for (int i = t; i < 512; i += 256) {
        int e = i >> 6, p = i & 63;
        sc[e][p] = scores[(b * 8 + e) * 9216 + (h0 + (p >> 5)) * 96 + (w0 + (p & 31))];
    }
    // ---- stage biases (experts + shared as e=8)
    for (int i = t; i < 1152; i += 256) {
        int e = i >> 7, co = i & 127;
        bia[e][co] = (e < 8) ? eb[(e << 7) + co] : sb[co];
    }
    __syncthreads();

    const int wv = t >> 6;
    const int l  = t & 63;
    const int lm = l & 15;   // m (A: co) / n (B: pixel) within frag
    const int lq = l >> 4;   // k-subgroup for A/B; row-group for D

    f32x4 acc[2][4], accE[2][4];
    #pragma unroll
    for (int i2 = 0; i2 < 2; i2++)
        #pragma unroll
        for (int j = 0; j < 4; j++) {
            acc[i2][j]  = (f32x4){0.f, 0.f, 0.f, 0.f};
            accE[i2][j] = (f32x4){0.f, 0.f, 0.f, 0.f};
        }

    const int bBase = lm * 136 + lq * 8;
    const uint4* pw4 = reinterpret_cast<const uint4*>(pw) + wv * 512 + l;

    uint4 afA[8], afB[8];   // A-frag double buffer: [kc*2+h]

#define LOADF(dst, etv) {                                                     \
    const uint4* _p = pw4 + (etv) * 2048;                                     \
    _Pragma("unroll")                                                         \
    for (int q = 0; q < 8; ++q) dst[q] = _p[(q >> 1) * 128 + (q & 1) * 64];   \
}

#define COMPUTE(src, etv) {                                                   \
    const int e_   = (etv) / 9;                                               \
    const int tap_ = (etv) - e_ * 9;                                          \
    const int kh_  = tap_ / 3;                                                \
    const int kw_  = tap_ - kh_ * 3;                                          \
    const int xr0  = kh_ * 4624 + kw_ * 136 + bBase;                          \
    _Pragma("unroll")                                                         \
    for (int kc = 0; kc < 4; ++kc) {                                          \
        const short8 a0 = *reinterpret_cast<const short8*>(&src[kc * 2 + 0]); \
        const short8 a1 = *reinterpret_cast<const short8*>(&src[kc * 2 + 1]); \
        _Pragma("unroll")                                                     \
        for (int j = 0; j < 4; ++j) {                                         \
            const short8 bv = *reinterpret_cast<const short8*>(               \
                &xs[xr0 + (j >> 1) * 4624 + (j & 1) * 2176 + kc * 32]);       \
            accE[0][j] = __builtin_amdgcn_mfma_f32_16x16x32_bf16(             \
                a0, bv, accE[0][j], 0, 0, 0);                                 \
            accE[1][j] = __builtin_amdgcn_mfma_f32_16x16x32_bf16(             \
                a1, bv, accE[1][j], 0, 0, 0);                                 \
        }                                                                     \
    }                                                                         \
    if (tap_ == 8) {  /* end of expert: weighted accumulate */                \
        _Pragma("unroll")                                                     \
        for (int j = 0; j < 4; ++j) {                                         \
            const int p = j * 16 + lm;                                        \
            const float s_ = (e_ < 8) ? sc[e_][p] : 1.0f;                     \
            _Pragma("unroll")                                                 \
            for (int i2 = 0; i2 < 2; ++i2)                                    \
                _Pragma("unroll")                                             \
                for (int rr = 0; rr < 4; ++rr) {                              \
                    const int co_ = wv * 32 + i2 * 16 + lq * 4 + rr;          \
                    acc[i2][j][rr] += s_ * (accE[i2][j][rr] + bia[e_][co_]);  \
                    accE[i2][j][rr] = 0.f;                                    \
                }                                                             \
        }                                                                     \
    }                                                                         \
}

    // barrier-free main loop: 81 (expert,tap) steps, A-frags double-buffered
    LOADF(afA, 0);
    for (int eu = 0; eu < 40; ++eu) {
        const int et0 = eu * 2;
        LOADF(afB, et0 + 1);
        COMPUTE(afA, et0);
        LOADF(afA, et0 + 2);     // et0+2 <= 80
        COMPUTE(afB, et0 + 1);
    }
    COMPUTE(afA, 80);
#undef COMPUTE
#undef LOADF

    // ---- store (D frag: col = lm -> pixel, row = lq*4+rr -> co)
    float* ob = out + b * 128 * 9216;
    #pragma unroll
    for (int i2 = 0; i2 < 2; i2++)
        #pragma unroll
        for (int rr = 0; rr < 4; rr++) {
            const int co = wv * 32 + i2 * 16 + lq * 4 + rr;
            #pragma unroll
            for (int j = 0; j < 4; j++) {
                const int hh = h0 + (j >> 1);
                const int ww = w0 + (j & 1) * 16 + lm;
                ob[co * 9216 + hh * 96 + ww] = acc[i2][j][rr];
            }
        }
}

// ---------------------------------------------------------------------------
extern "C" void kernel_launch(void* const* d_in, const int* in_sizes, int n_in,
                              void* d_out, int out_size, void* d_ws, size_t ws_size,
                              hipStream_t stream) {
    const float* x  = (const float*)d_in[0];
    const float* gw = (const float*)d_in[1];
    const float* gb = (const float*)d_in[2];
    const float* ew = (const float*)d_in[3];
    const float* eb = (const float*)d_in[4];
    const float* sw = (const float*)d_in[5];
    const float* sb = (const float*)d_in[6];
    float* out = (float*)d_out;

    unsigned short* pw = (unsigned short*)d_ws;                  // 2,654,208 B
    float* scores = (float*)((char*)d_ws + 2654208);             // 1,179,648 B

    gate_prep_kernel<<<720, 256, 0, stream>>>(x, gw, gb, ew, sw, scores, pw);
    moe_main_kernel<<<576, 256, 0, stream>>>(x, pw, scores, eb, sb, out);
}